// Round 12
// baseline (707.629 us; speedup 1.0000x reference)
//
#include <hip/hip_runtime.h>
#include <math.h>

// SoftMSM loss on MI355X — round 11.
// CROSS-BLOCK column-strip pipeline: 4 blocks per problem (256 blocks total,
// 1 per CU -> co-resident by capacity), each block owns 128 cols (G=2/lane).
// R10's verified cell math / DPP / scale machinery verbatim, G=2.
//
// Rationale (fit of R3-R10): all schedules land at ~34 issued cyc/cell — we
// are issue-bound on ONE SIMD per problem at the chip's low-occupancy clock.
// The only lever left is more SIMDs per problem => split cols across blocks.
//
// Seam (strip s-1 -> s): per row-pair p the producer's lane 63 stores
// {r0,r1,r2,kacc} = exactly the DPP payload, to global seam[b][s-1][p];
// publishes progress every 4 pairs via __threadfence + atomicExch (device
// scope). Consumer (lane 0 of strip s) polls the counter with s_sleep +
// acquire fence; in-block skew (63 steps) keeps the producer ~63 pairs
// ahead, so polls are ~1 per 63 steps and seam loads prefetch 1 step ahead.
//
// d_ws layout: [0,256): 64 float results | [256,1280): 256 int progress |
// [2048, 2048+786432): seam float4[64][3][256].  (~790 KB)

#define TT 512
#define BATCH 64
#define NSTRIP 4
#define G 2                      // cols per lane
#define NP (TT / 2)              // 256 row-pairs
#define STEPS (NP + 63)          // 319
#define CHUNK 4

#define C1F 1.2011224087864498f  // sqrt(log2 e)
#define C2F 2.8853900817779268f  // 2*log2 e
#define K2F 0.13533528323661270f // e^-2
#define LN2F 0.69314718055994531f

#if __has_builtin(__builtin_amdgcn_exp2f)
#define EXP2F(x) __builtin_amdgcn_exp2f(x)
#else
#define EXP2F(x) __expf((x) * LN2F)
#endif

typedef float v2f __attribute__((ext_vector_type(2)));

__device__ __forceinline__ float dpp_shr1_f(float src, float old) {
  return __int_as_float(__builtin_amdgcn_update_dpp(
      __float_as_int(old), __float_as_int(src), 0x138, 0xF, 0xF, false));
}
__device__ __forceinline__ int dpp_shr1_i(int src, int old) {
  return __builtin_amdgcn_update_dpp(old, src, 0x138, 0xF, 0xF, false);
}

__global__ __launch_bounds__(64, 1) void msm_kernel(const float* __restrict__ x,
                                                    const float* __restrict__ y,
                                                    float* __restrict__ res,
                                                    int* __restrict__ prog,
                                                    float4* __restrict__ seam) {
  const int bid = blockIdx.x;
  const int b = bid >> 2;            // problem
  const int s = bid & 3;             // strip: cols [128s, 128s+128)
  const int j = threadIdx.x;         // 0..63; owns cols 128s+2j, +1

  __shared__ float2 XC2[NP], DX2[NP], EX2[NP];

  // ---- x staging (full 512 rows, every block; R10 verbatim) ----
  {
    const float4* xv = (const float4*)(x + b * TT);
    float4 a0 = xv[j * 2], a1 = xv[j * 2 + 1];
    float rx[8] = {a0.x, a0.y, a0.z, a0.w, a1.x, a1.y, a1.z, a1.w};
    float prev = (j > 0) ? x[b * TT + 8 * j - 1] : 0.0f;
    float cc[8], dd[8], ee[8];
#pragma unroll
    for (int k = 0; k < 8; ++k) {
      float dx = rx[k] - prev;       // row 0's dx unused (up input is 0)
      prev = rx[k];
      cc[k] = rx[k] * C1F;
      dd[k] = dx;
      ee[k] = __expf(-dx * dx);
    }
#pragma unroll
    for (int q = 0; q < 4; ++q) {
      XC2[4 * j + q] = make_float2(cc[2 * q], cc[2 * q + 1]);
      DX2[4 * j + q] = make_float2(dd[2 * q], dd[2 * q + 1]);
      EX2[4 * j + q] = make_float2(ee[2 * q], ee[2 * q + 1]);
    }
  }
  // ---- y: this strip's 2 cols per lane ----
  float yc[G], dyS[G], edy2[G];
  {
    const int cbase = s * 128 + 2 * j;
    float y0 = y[b * TT + cbase];
    float y1 = y[b * TT + cbase + 1];
    float prev = (cbase > 0) ? y[b * TT + cbase - 1] : 0.0f;  // real col for s>0,j=0
    float ry[G] = {y0, y1};
#pragma unroll
    for (int k = 0; k < G; ++k) {
      float dy = ry[k] - prev;       // global col 0's dy unused (left input 0)
      prev = ry[k];
      yc[k] = ry[k] * C1F;
      dyS[k] = dy;
      edy2[k] = __expf(-dy * dy);
    }
  }
  __syncthreads();

  float Ep0 = 0.0f, Ep1 = 0.0f;                // F[2p-1, owned cols]
  float dc0 = 0.0f, dc1 = 0.0f, dc2 = 0.0f;    // lastcol(2p-1, 2p, 2p+1)
  int kacc = 0;

  const int* progsrc = prog + (b * 4 + s - 1);
  int* progdst = prog + (b * 4 + s);
  const float4* seamsrc = seam + (size_t)(b * 3 + s - 1) * NP;
  float4* seamdst = seam + (size_t)(b * 3 + s) * NP;
  int known = 0;
  float4 smN = make_float4(0.f, 0.f, 0.f, 0.f);

  if (s > 0 && j == 0) {                       // pre-loop: fetch seam[0]
    int v = atomicAdd((int*)progsrc, 0);
    while (v < 1) { __builtin_amdgcn_s_sleep(32); v = atomicAdd((int*)progsrc, 0); }
    known = v;
    __threadfence();
    smN = seamsrc[0];
  }

  float2 nxc = XC2[0], ndx = DX2[0], nex = EX2[0];

  for (int t = 0; t < STEPS; ++t) {
    float r0 = dpp_shr1_f(dc0, 0.0f);
    float r1 = dpp_shr1_f(dc1, 0.0f);
    float r2 = dpp_shr1_f(dc2, 0.0f);
    int k_in = dpp_shr1_i(kacc, kacc);
    const int p = t - j;
    if (s == 0) {
      if (t == 0 && j == 0) r0 = K2F;          // global seed F[-1,-1] = e^{-2}
    } else if (j == 0 && p >= 0 && p < NP) {
      r0 = smN.x; r1 = smN.y; r2 = smN.z;      // prefetched seam[p]
      k_in = __float_as_int(smN.w);
      int pn = (p + 1 < NP) ? p + 1 : NP - 1;  // prefetch seam[p+1]
      if (pn >= known) {
        int v = atomicAdd((int*)progsrc, 0);
        while (v <= pn) { __builtin_amdgcn_s_sleep(32); v = atomicAdd((int*)progsrc, 0); }
        known = v;
        __threadfence();
      }
      smN = seamsrc[pn];
    }
    const float2 cxc = nxc, cdx = ndx, cex = nex;
    {
      int pn = t + 1 - j;
      pn = (pn < 0) ? 0 : ((pn > NP - 1) ? NP - 1 : pn);
      nxc = XC2[pn]; ndx = DX2[pn]; nex = EX2[pn];
    }

    if (p >= 0 && p < NP) {
      if (p == 0) kacc = k_in;                 // pipeline entry: adopt scale
      const int knew = (k_in > kacc) ? k_in : kacc;
      const float mMe = ldexpf(1.0f, kacc - knew);  // <= 1
      const float mIn = ldexpf(1.0f, k_in - knew);  // <= 1
      kacc = knew;
      const float dv0 = r0 * mIn, dv1 = r1 * mIn, dv2 = r2 * mIn;
      const float nd0 = dc2 * mMe;
      const float u0 = Ep0 * mMe, u1 = Ep1 * mMe;

      // ---- weights, packed over the row pair (R10 verbatim, G=2) ----
      const v2f xcp = {cxc.x, cxc.y};
      const v2f dxp = {cdx.x, cdx.y};
      const v2f exp_ = {cex.x, cex.y};
      v2f A2[G], B2[G], C2[G];
#pragma unroll
      for (int k = 0; k < G; ++k) {
        v2f s1 = xcp - yc[k];
        v2f arg = C2F - s1 * s1;
        v2f A;
        A.x = EXP2F(arg.x);
        A.y = EXP2F(arg.y);
        v2f Em = A * K2F;
        v2f Bs = exp_ + Em;
        v2f Cs = edy2[k] + Em;
        v2f gu = dxp * s1;
        v2f gl = dyS[k] * s1;
        A2[k] = A;
        B2[k].x = (gu.x > 0.0f) ? Bs.x : 1.0f;
        B2[k].y = (gu.y > 0.0f) ? Bs.y : 1.0f;
        C2[k].x = (gl.x < 0.0f) ? Cs.x : 1.0f;
        C2[k].y = (gl.y < 0.0f) ? Cs.y : 1.0f;
      }
      __builtin_amdgcn_sched_barrier(0);

      // ---- pure-FMA chains ----
      float pa0 = __fmaf_rn(dv0, A2[0].x, u0 * B2[0].x);
      float pa1 = __fmaf_rn(u0, A2[1].x, u1 * B2[1].x);
      float T00 = __fmaf_rn(dv1, C2[0].x, pa0);
      float T01 = __fmaf_rn(T00, C2[1].x, pa1);
      float pb0 = __fmaf_rn(dv1, A2[0].y, T00 * B2[0].y);
      float pb1 = __fmaf_rn(T00, A2[1].y, T01 * B2[1].y);
      float T10 = __fmaf_rn(dv2, C2[0].y, pb0);
      float T11 = __fmaf_rn(T10, C2[1].y, pb1);

      dc0 = nd0;
      dc1 = T01;
      float vmax = fmaxf(fmaxf(T10, T11), fmaxf(dc0, dc1));
      unsigned ue = (__float_as_uint(vmax) >> 23) & 0xFFu;
      int e = (int)ue - 126;
      float sc = ldexpf(1.0f, -e);
      Ep0 = T10 * sc; Ep1 = T11 * sc;
      dc0 *= sc; dc1 *= sc; dc2 = Ep1;
      kacc += e;

      if (s < NSTRIP - 1 && j == 63) {         // producer: publish pair p
        seamdst[p] = make_float4(dc0, dc1, dc2, __int_as_float(kacc));
        if ((p & (CHUNK - 1)) == CHUNK - 1 || p == NP - 1) {
          __threadfence();                     // drain stores device-wide
          atomicExch(progdst, p + 1);          // release publish
        }
      }
    }
  }

  if (s == NSTRIP - 1 && j == 63) {
    res[b] = 1022.0f - (__logf(Ep1) + (float)kacc * LN2F);
  }
}

__global__ __launch_bounds__(256) void zero_prog_kernel(int* __restrict__ prog) {
  prog[threadIdx.x] = 0;
}

__global__ __launch_bounds__(64) void reduce_kernel(const float* __restrict__ res,
                                                    float* __restrict__ out) {
  float v = res[threadIdx.x];
#pragma unroll
  for (int off = 32; off > 0; off >>= 1) v += __shfl_down(v, off);
  if (threadIdx.x == 0) out[0] = v * (1.0f / BATCH);
}

extern "C" void kernel_launch(void* const* d_in, const int* in_sizes, int n_in,
                              void* d_out, int out_size, void* d_ws, size_t ws_size,
                              hipStream_t stream) {
  const float* x = (const float*)d_in[0];
  const float* y = (const float*)d_in[1];
  float* out = (float*)d_out;
  char* ws = (char*)d_ws;
  float* res = (float*)ws;                     // 64 floats
  int* prog = (int*)(ws + 256);                // 256 ints
  float4* seam = (float4*)(ws + 2048);         // 64*3*256 float4 = 768 KB
  zero_prog_kernel<<<1, 256, 0, stream>>>(prog);
  msm_kernel<<<BATCH * NSTRIP, 64, 0, stream>>>(x, y, res, prog, seam);
  reduce_kernel<<<1, 64, 0, stream>>>(res, out);
}

// Round 13
// 209.395 us; speedup vs baseline: 3.3794x; 3.3794x over previous
//
#include <hip/hip_runtime.h>
#include <math.h>

// SoftMSM loss on MI355X — round 12.
// Single-wave skewed pipeline (R8/R10 skeleton, verified absmax 0.0) with
// IN-WAVE SOFTWARE PIPELINING: GCN issues in order per wave, so R9/R10's
// weight phase -> chain phase layout left the serial chain+normalize tail
// (~500 cyc of dependent latency) exposed every step. Here step t+1's
// weights (independent: prefetched row data + per-lane y regs) are
// interleaved cell-by-cell between step t's chain FMAs, fenced with
// sched_barrier(0) per cell; unroll-by-2 with ping-pong weight banks avoids
// register copies. Everything computed unconditionally; only the state
// commit (Ep/dc/kacc) is predicated -> one uniform instruction stream, and
// a lane builds its step-(t+1) weights at step t even before it activates.
//
// Recursion (c=1, gamma=1), F = e^{i+j} * exp(-cost):
//   F[i,j] = F[i-1,j-1]*A + F[i-1,j]*B + F[i,j-1]*C
//   A = e^{2-m2}; B = (dx*(x-y)>0 ? ex2+Em : 1); C = (dy*(x-y)<0 ? edy2+Em : 1)
//   cost = 1022 - log(F[511,511])
// Lane j owns cols [8j, 8j+8); step t handles row-pair p = t - j.
// Boundary via DPP wave_shr:1. Scale 2^kacc rebased to max(kacc, k_in)
// (shifts <= 0, overflow-proof); per-step normalize into [0.5, 1).

#define TT 512
#define BATCH 64
#define G 8                      // cols per lane
#define NP (TT / 2)              // 256 row-pairs
#define STEPS (NP + 63)          // 319 (unroll-2 runs step 319 too: inert)

#define C1F 1.2011224087864498f  // sqrt(log2 e)
#define C2F 2.8853900817779268f  // 2*log2 e
#define K2F 0.13533528323661270f // e^-2
#define LN2F 0.69314718055994531f

#if __has_builtin(__builtin_amdgcn_exp2f)
#define EXP2F(x) __builtin_amdgcn_exp2f(x)
#else
#define EXP2F(x) __expf((x) * LN2F)
#endif

typedef float v2f __attribute__((ext_vector_type(2)));

// lane i gets lane i-1's src; lane 0 gets `old`  (wave_shr:1 = 0x138)
__device__ __forceinline__ float dpp_shr1_f(float src, float old) {
  return __int_as_float(__builtin_amdgcn_update_dpp(
      __float_as_int(old), __float_as_int(src), 0x138, 0xF, 0xF, false));
}
__device__ __forceinline__ int dpp_shr1_i(int src, int old) {
  return __builtin_amdgcn_update_dpp(old, src, 0x138, 0xF, 0xF, false);
}

__global__ __launch_bounds__(64, 1) void msm_kernel(const float* __restrict__ x,
                                                    const float* __restrict__ y,
                                                    float* __restrict__ ws) {
  const int b = blockIdx.x;
  const int j = threadIdx.x;         // 0..63

  __shared__ float2 XC2[NP];         // {xc(2p), xc(2p+1)}, xc = x * C1
  __shared__ float2 DX2[NP];         // {dx(2p), dx(2p+1)}
  __shared__ float2 EX2[NP];         // {exp(-dx^2) pair}

  // ---- setup: x-derived row data (R10 verbatim) ----
  {
    const float4* xv = (const float4*)(x + b * TT);
    float4 a0 = xv[j * 2], a1 = xv[j * 2 + 1];
    float rx[G] = {a0.x, a0.y, a0.z, a0.w, a1.x, a1.y, a1.z, a1.w};
    float prev = (j > 0) ? x[b * TT + 8 * j - 1] : 0.0f;
    float cc[G], dd[G], ee[G];
#pragma unroll
    for (int k = 0; k < G; ++k) {
      float dx = rx[k] - prev;       // row 0's dx unused (up input is 0)
      prev = rx[k];
      cc[k] = rx[k] * C1F;
      dd[k] = dx;
      ee[k] = __expf(-dx * dx);
    }
#pragma unroll
    for (int q = 0; q < 4; ++q) {
      XC2[4 * j + q] = make_float2(cc[2 * q], cc[2 * q + 1]);
      DX2[4 * j + q] = make_float2(dd[2 * q], dd[2 * q + 1]);
      EX2[4 * j + q] = make_float2(ee[2 * q], ee[2 * q + 1]);
    }
  }
  // ---- setup: y-derived column registers ----
  float yc[G], dyS[G], edy2[G];
  {
    const float4* yv = (const float4*)(y + b * TT);
    float4 a0 = yv[j * 2], a1 = yv[j * 2 + 1];
    float ry[G] = {a0.x, a0.y, a0.z, a0.w, a1.x, a1.y, a1.z, a1.w};
    float prev = (j > 0) ? y[b * TT + 8 * j - 1] : 0.0f;
#pragma unroll
    for (int k = 0; k < G; ++k) {
      float dy = ry[k] - prev;       // col 0's dy unused (left input is 0)
      prev = ry[k];
      yc[k] = ry[k] * C1F;
      dyS[k] = dy;
      edy2[k] = __expf(-dy * dy);
    }
  }
  __syncthreads();

  float Ep[G];                       // F[2p-1, owned cols], lane scale 2^kacc
#pragma unroll
  for (int k = 0; k < G; ++k) Ep[k] = 0.0f;
  float dc0 = 0.0f, dc1 = 0.0f, dc2 = 0.0f;  // lastcol(2p-1, 2p, 2p+1)
  int kacc = 0;

  // weight banks (ping-pong) and row-data banks
  v2f Aw[2][G], Bw[2][G], Cw[2][G];
  float2 rdEx, rdEd, rdEe;           // row data for odd-step W-builds
  float2 rdOx, rdOd, rdOe;           // row data for even-step W-builds

  // build a W cell (packed over the row pair) — pure function of row data
#define WCELL(bank, kk, xcU, dxU, exU)                                  \
  {                                                                     \
    v2f s1 = v2f{(xcU).x, (xcU).y} - yc[kk];                            \
    v2f arg = C2F - s1 * s1;                                            \
    v2f A;                                                              \
    A.x = EXP2F(arg.x);                                                 \
    A.y = EXP2F(arg.y);                                                 \
    v2f Em = A * K2F;                                                   \
    v2f Bs = v2f{(exU).x, (exU).y} + Em;                                \
    v2f Cs = edy2[kk] + Em;                                             \
    v2f gu = v2f{(dxU).x, (dxU).y} * s1;                                \
    v2f gl = dyS[kk] * s1;                                              \
    Aw[bank][kk] = A;                                                   \
    Bw[bank][kk].x = (gu.x > 0.0f) ? Bs.x : 1.0f;                       \
    Bw[bank][kk].y = (gu.y > 0.0f) ? Bs.y : 1.0f;                       \
    Cw[bank][kk].x = (gl.x < 0.0f) ? Cs.x : 1.0f;                       \
    Cw[bank][kk].y = (gl.y < 0.0f) ? Cs.y : 1.0f;                       \
  }

  // ---- pre-loop: W bank 0 = weights for step 0; rdE = data(step 1) ----
  {
    float2 x0 = XC2[0], d0 = DX2[0], e0 = EX2[0];  // clamp(0-j) == 0
#pragma unroll
    for (int k = 0; k < G; ++k) WCELL(0, k, x0, d0, e0)
    int p1 = 1 - j;
    p1 = (p1 < 0) ? 0 : p1;
    rdEx = XC2[p1]; rdEd = DX2[p1]; rdEe = EX2[p1];
  }

  // one DP step: uses W[cur]; builds W[nxt] for step t+1 from (xcU,dxU,exU);
  // loads row data for step t+2 into (xcL,dxL,exL)
  auto do_step = [&](int t, int cur, int nxt,
                     float2& xcU, float2& dxU, float2& exU,
                     float2& xcL, float2& dxL, float2& exL) {
    // prefetch data(t+2) — latency hidden under this step's compute
    {
      int pn = t + 2 - j;
      pn = (pn < 0) ? 0 : ((pn > NP - 1) ? NP - 1 : pn);
      xcL = XC2[pn]; dxL = DX2[pn]; exL = EX2[pn];
    }
    // DPP boundary exchange (VALU pipe)
    float r0 = dpp_shr1_f(dc0, 0.0f);
    float r1 = dpp_shr1_f(dc1, 0.0f);
    float r2 = dpp_shr1_f(dc2, 0.0f);
    int k_in = dpp_shr1_i(kacc, kacc);       // lane 0 keeps own kacc
    if (t == 0 && j == 0) r0 = K2F;          // global seed F[-1,-1] = e^{-2}
    const int p = t - j;
    const bool act = (p >= 0) && (p < NP);
    // rebase (pure; committed only if act)
    int kacc_e = (p == 0) ? k_in : kacc;     // pipeline entry: adopt scale
    int knew = (k_in > kacc_e) ? k_in : kacc_e;
    float mMe = ldexpf(1.0f, kacc_e - knew); // <= 1
    float mIn = ldexpf(1.0f, k_in - knew);   // <= 1
    float dv0 = r0 * mIn, dv1 = r1 * mIn, dv2 = r2 * mIn;
    float nd0 = dc2 * mMe;
    // interleaved: W[nxt] cell k  +  chain col k with W[cur]
    float u[G], T0[G], T1[G];
#pragma unroll
    for (int k = 0; k < G; ++k) {
      WCELL(nxt, k, xcU, dxU, exU)
      u[k] = Ep[k] * mMe;
      float da = (k == 0) ? dv0 : u[k - 1];
      float pa = __fmaf_rn(da, Aw[cur][k].x, u[k] * Bw[cur][k].x);
      T0[k] = __fmaf_rn((k == 0) ? dv1 : T0[k - 1], Cw[cur][k].x, pa);
      float db = (k == 0) ? dv1 : T0[k - 1];
      float pb = __fmaf_rn(db, Aw[cur][k].y, T0[k] * Bw[cur][k].y);
      T1[k] = __fmaf_rn((k == 0) ? dv2 : T1[k - 1], Cw[cur][k].y, pb);
      __builtin_amdgcn_sched_barrier(0);     // pin the W/chain interleave
    }
    // normalize + masked commit
    float ndc1 = T0[G - 1];
    float vmax = fmaxf(fmaxf(fmaxf(T1[0], T1[1]), fmaxf(T1[2], T1[3])),
                       fmaxf(fmaxf(T1[4], T1[5]), fmaxf(T1[6], T1[7])));
    vmax = fmaxf(vmax, fmaxf(nd0, ndc1));
    unsigned ue = (__float_as_uint(vmax) >> 23) & 0xFFu;
    int e = (int)ue - 126;
    float sc = ldexpf(1.0f, -e);
#pragma unroll
    for (int k = 0; k < G; ++k) Ep[k] = act ? T1[k] * sc : Ep[k];
    dc0 = act ? nd0 * sc : dc0;
    dc1 = act ? ndc1 * sc : dc1;
    dc2 = act ? T1[G - 1] * sc : dc2;
    kacc = act ? knew + e : kacc;
  };

  for (int t = 0; t < STEPS; t += 2) {
    do_step(t,     0, 1, rdEx, rdEd, rdEe, rdOx, rdOd, rdOe);
    do_step(t + 1, 1, 0, rdOx, rdOd, rdOe, rdEx, rdEd, rdEe);
  }
#undef WCELL

  if (j == 63) {
    // cost = 1022 - log(F_true)
    ws[b] = 1022.0f - (__logf(Ep[G - 1]) + (float)kacc * LN2F);
  }
}

__global__ __launch_bounds__(64) void reduce_kernel(const float* __restrict__ ws,
                                                    float* __restrict__ out) {
  float v = ws[threadIdx.x];
#pragma unroll
  for (int off = 32; off > 0; off >>= 1) v += __shfl_down(v, off);
  if (threadIdx.x == 0) out[0] = v * (1.0f / BATCH);
}

extern "C" void kernel_launch(void* const* d_in, const int* in_sizes, int n_in,
                              void* d_out, int out_size, void* d_ws, size_t ws_size,
                              hipStream_t stream) {
  const float* x = (const float*)d_in[0];
  const float* y = (const float*)d_in[1];
  float* ws = (float*)d_ws;
  float* out = (float*)d_out;
  msm_kernel<<<BATCH, 64, 0, stream>>>(x, y, ws);
  reduce_kernel<<<1, 64, 0, stream>>>(ws, out);
}

// Round 14
// 203.037 us; speedup vs baseline: 3.4852x; 1.0313x over previous
//
#include <hip/hip_runtime.h>
#include <math.h>
#include <type_traits>

// SoftMSM loss on MI355X — round 13.
// R12 skeleton (single-wave, DPP exchange, verified absmax 0.0) with
// exec-cycle trims: R12's VGPR=88 showed the cross-step weight banks never
// fully materialized; VALUBusy ~81% on the active SIMD says we're
// VALU-execution-bound with ~1.5x codegen fat.
//   1. 3-phase time loop: steady phase (t in [64,256), 192/319 steps) has ALL
//      lanes active -> drops act cmps, 12+ commit cndmasks, entry/seed logic.
//   2. sliding-window-3 weight lookahead WITHIN the step (W(k+3) built before
//      chain(k), sched_barrier-fenced): exp latency covered at 1/3 the
//      register cost of R12's cross-step double bank.
//   3. Bs/Cs via pk-fma (A*K2+ex2), vmax tree shaped for v_max3_f32.
//
// Recursion (c=1, gamma=1), F = e^{i+j} * exp(-cost):
//   F[i,j] = F[i-1,j-1]*A + F[i-1,j]*B + F[i,j-1]*C
//   A = e^{2-m2}; B = (dx*(x-y)>0 ? ex2+Em : 1); C = (dy*(x-y)<0 ? edy2+Em : 1)
//   cost = 1022 - log(F[511,511])
// Lane j owns cols [8j,8j+8); step t handles row-pair p = t-j. DPP wave_shr:1
// boundary; scale 2^kacc rebased to max(kacc,k_in); per-step normalize.

#define TT 512
#define BATCH 64
#define G 8
#define NP (TT / 2)              // 256 row-pairs
// phases: [0,64) ramp-up, [64,256) steady, [256,320) ramp-down (319 inert)

#define C1F 1.2011224087864498f  // sqrt(log2 e)
#define C2F 2.8853900817779268f  // 2*log2 e
#define K2F 0.13533528323661270f // e^-2
#define LN2F 0.69314718055994531f

#if __has_builtin(__builtin_amdgcn_exp2f)
#define EXP2F(x) __builtin_amdgcn_exp2f(x)
#else
#define EXP2F(x) __expf((x) * LN2F)
#endif

typedef float v2f __attribute__((ext_vector_type(2)));

__device__ __forceinline__ float dpp_shr1_f(float src, float old) {
  return __int_as_float(__builtin_amdgcn_update_dpp(
      __float_as_int(old), __float_as_int(src), 0x138, 0xF, 0xF, false));
}
__device__ __forceinline__ int dpp_shr1_i(int src, int old) {
  return __builtin_amdgcn_update_dpp(old, src, 0x138, 0xF, 0xF, false);
}

__global__ __launch_bounds__(64, 1) void msm_kernel(const float* __restrict__ x,
                                                    const float* __restrict__ y,
                                                    float* __restrict__ ws) {
  const int b = blockIdx.x;
  const int j = threadIdx.x;         // 0..63

  __shared__ float2 XC2[NP];         // {xc(2p), xc(2p+1)}, xc = x * C1
  __shared__ float2 DX2[NP];
  __shared__ float2 EX2[NP];

  // ---- setup (R12 verbatim) ----
  {
    const float4* xv = (const float4*)(x + b * TT);
    float4 a0 = xv[j * 2], a1 = xv[j * 2 + 1];
    float rx[G] = {a0.x, a0.y, a0.z, a0.w, a1.x, a1.y, a1.z, a1.w};
    float prev = (j > 0) ? x[b * TT + 8 * j - 1] : 0.0f;
    float cc[G], dd[G], ee[G];
#pragma unroll
    for (int k = 0; k < G; ++k) {
      float dx = rx[k] - prev;
      prev = rx[k];
      cc[k] = rx[k] * C1F;
      dd[k] = dx;
      ee[k] = __expf(-dx * dx);
    }
#pragma unroll
    for (int q = 0; q < 4; ++q) {
      XC2[4 * j + q] = make_float2(cc[2 * q], cc[2 * q + 1]);
      DX2[4 * j + q] = make_float2(dd[2 * q], dd[2 * q + 1]);
      EX2[4 * j + q] = make_float2(ee[2 * q], ee[2 * q + 1]);
    }
  }
  float yc[G], dyS[G], edy2[G];
  {
    const float4* yv = (const float4*)(y + b * TT);
    float4 a0 = yv[j * 2], a1 = yv[j * 2 + 1];
    float ry[G] = {a0.x, a0.y, a0.z, a0.w, a1.x, a1.y, a1.z, a1.w};
    float prev = (j > 0) ? y[b * TT + 8 * j - 1] : 0.0f;
#pragma unroll
    for (int k = 0; k < G; ++k) {
      float dy = ry[k] - prev;
      prev = ry[k];
      yc[k] = ry[k] * C1F;
      dyS[k] = dy;
      edy2[k] = __expf(-dy * dy);
    }
  }
  __syncthreads();

  float Ep[G];
#pragma unroll
  for (int k = 0; k < G; ++k) Ep[k] = 0.0f;
  float dc0 = 0.0f, dc1 = 0.0f, dc2 = 0.0f;  // lastcol(2p-1, 2p, 2p+1)
  int kacc = 0;

  float2 rdEx, rdEd, rdEe, rdOx, rdOd, rdOe;
  {                                   // data for step 0 (even bank)
    rdEx = XC2[0]; rdEd = DX2[0]; rdEe = EX2[0];   // clamp(0-j) == 0
  }

  // PH: 0 = ramp-up, 1 = steady, 2 = ramp-down
  auto step_fn = [&](int t, auto phc, float2& xcU, float2& dxU, float2& exU,
                     float2& xcL, float2& dxL, float2& exL) {
    constexpr int PH = decltype(phc)::value;
    // prefetch data(t+2) into the other bank
    {
      int pn = t + 2 - j;
      pn = (pn < 0) ? 0 : ((pn > NP - 1) ? NP - 1 : pn);
      xcL = XC2[pn]; dxL = DX2[pn]; exL = EX2[pn];
    }
    // DPP boundary exchange
    float r0 = dpp_shr1_f(dc0, 0.0f);
    float r1 = dpp_shr1_f(dc1, 0.0f);
    float r2 = dpp_shr1_f(dc2, 0.0f);
    int k_in = dpp_shr1_i(kacc, kacc);
    const int p = t - j;
    if (PH == 0) {
      if (t == 0 && j == 0) r0 = K2F;        // global seed F[-1,-1] = e^{-2}
    }
    bool act = true;
    int kacc_e = kacc;
    if (PH == 0) {
      act = (p >= 0);
      kacc_e = (p == 0) ? k_in : kacc;       // pipeline entry: adopt scale
    } else if (PH == 2) {
      act = (p < NP);
    }
    const int knew = (k_in > kacc_e) ? k_in : kacc_e;
    const float mMe = ldexpf(1.0f, kacc_e - knew);  // <= 1
    const float mIn = ldexpf(1.0f, k_in - knew);    // <= 1
    const float dv0 = r0 * mIn, dv1 = r1 * mIn, dv2 = r2 * mIn;
    const float nd0 = dc2 * mMe;
    float u[G];
#pragma unroll
    for (int k = 0; k < G; ++k) u[k] = Ep[k] * mMe;

    const v2f xcp = {xcU.x, xcU.y};
    const v2f dxp = {dxU.x, dxU.y};
    const v2f exv = {exU.x, exU.y};
    v2f Aw[G], Bw[G], Cw[G];
#define WCELL(kk)                                                       \
    {                                                                   \
      v2f s1 = xcp - yc[kk];                                            \
      v2f arg = C2F - s1 * s1;                                          \
      v2f A;                                                            \
      A.x = EXP2F(arg.x);                                               \
      A.y = EXP2F(arg.y);                                               \
      v2f Bs = A * K2F + exv;       /* pk fma */                        \
      v2f Cs = A * K2F + edy2[kk];  /* pk fma */                        \
      v2f gu = dxp * s1;                                                \
      v2f gl = dyS[kk] * s1;                                            \
      Aw[kk] = A;                                                       \
      Bw[kk].x = (gu.x > 0.0f) ? Bs.x : 1.0f;                           \
      Bw[kk].y = (gu.y > 0.0f) ? Bs.y : 1.0f;                           \
      Cw[kk].x = (gl.x < 0.0f) ? Cs.x : 1.0f;                           \
      Cw[kk].y = (gl.y < 0.0f) ? Cs.y : 1.0f;                           \
    }
    WCELL(0) WCELL(1) WCELL(2)
    float T0[G], T1[G];
#pragma unroll
    for (int k = 0; k < G; ++k) {
      if (k + 3 < G) WCELL(k + 3)
      __builtin_amdgcn_sched_barrier(0);     // window stays ahead of chain
      float da = (k == 0) ? dv0 : u[k - 1];
      float pa = __fmaf_rn(da, Aw[k].x, u[k] * Bw[k].x);
      T0[k] = __fmaf_rn((k == 0) ? dv1 : T0[k - 1], Cw[k].x, pa);
      float db = (k == 0) ? dv1 : T0[k - 1];
      float pb = __fmaf_rn(db, Aw[k].y, T0[k] * Bw[k].y);
      T1[k] = __fmaf_rn((k == 0) ? dv2 : T1[k - 1], Cw[k].y, pb);
    }
#undef WCELL
    const float ndc1 = T0[G - 1];
    // vmax shaped for v_max3
    float m0 = fmaxf(fmaxf(T1[0], T1[1]), T1[2]);
    float m1 = fmaxf(fmaxf(T1[3], T1[4]), T1[5]);
    float m2 = fmaxf(fmaxf(T1[6], T1[7]), nd0);
    float vmax = fmaxf(fmaxf(m0, m1), fmaxf(m2, ndc1));
    unsigned ue = (__float_as_uint(vmax) >> 23) & 0xFFu;
    int e = (int)ue - 126;
    float sc = ldexpf(1.0f, -e);
    if (PH == 1) {                           // steady: unconditional commit
#pragma unroll
      for (int k = 0; k < G; ++k) Ep[k] = T1[k] * sc;
      dc0 = nd0 * sc;
      dc1 = ndc1 * sc;
      dc2 = Ep[G - 1];
      kacc = knew + e;
    } else {                                 // ramp: masked commit
#pragma unroll
      for (int k = 0; k < G; ++k) Ep[k] = act ? T1[k] * sc : Ep[k];
      dc0 = act ? nd0 * sc : dc0;
      dc1 = act ? ndc1 * sc : dc1;
      dc2 = act ? Ep[G - 1] : dc2;
      kacc = act ? knew + e : kacc;
    }
  };

  std::integral_constant<int, 0> PH0;
  std::integral_constant<int, 1> PH1;
  std::integral_constant<int, 2> PH2;
  for (int t = 0; t < 64; t += 2) {
    step_fn(t,     PH0, rdEx, rdEd, rdEe, rdOx, rdOd, rdOe);
    step_fn(t + 1, PH0, rdOx, rdOd, rdOe, rdEx, rdEd, rdEe);
  }
  for (int t = 64; t < 256; t += 2) {
    step_fn(t,     PH1, rdEx, rdEd, rdEe, rdOx, rdOd, rdOe);
    step_fn(t + 1, PH1, rdOx, rdOd, rdOe, rdEx, rdEd, rdEe);
  }
  for (int t = 256; t < 320; t += 2) {       // step 319 inert (all p >= NP)
    step_fn(t,     PH2, rdEx, rdEd, rdEe, rdOx, rdOd, rdOe);
    step_fn(t + 1, PH2, rdOx, rdOd, rdOe, rdEx, rdEd, rdEe);
  }

  if (j == 63) {
    ws[b] = 1022.0f - (__logf(Ep[G - 1]) + (float)kacc * LN2F);
  }
}

__global__ __launch_bounds__(64) void reduce_kernel(const float* __restrict__ ws,
                                                    float* __restrict__ out) {
  float v = ws[threadIdx.x];
#pragma unroll
  for (int off = 32; off > 0; off >>= 1) v += __shfl_down(v, off);
  if (threadIdx.x == 0) out[0] = v * (1.0f / BATCH);
}

extern "C" void kernel_launch(void* const* d_in, const int* in_sizes, int n_in,
                              void* d_out, int out_size, void* d_ws, size_t ws_size,
                              hipStream_t stream) {
  const float* x = (const float*)d_in[0];
  const float* y = (const float*)d_in[1];
  float* ws = (float*)d_ws;
  float* out = (float*)d_out;
  msm_kernel<<<BATCH, 64, 0, stream>>>(x, y, ws);
  reduce_kernel<<<1, 64, 0, stream>>>(ws, out);
}

// Round 15
// 166.876 us; speedup vs baseline: 4.2404x; 1.2167x over previous
//
#include <hip/hip_runtime.h>
#include <math.h>
#include <type_traits>

// SoftMSM loss on MI355X — round 14: BIDIRECTIONAL meet-in-the-middle.
// E-space path-sum DP splits exactly at the row-255/256 seam:
//   E_total = sum_j Gb[256,j] * ( Em(256,j)*E[255,j-1] + Wu(256,j)*E[255,j] )
// Wave 0: rows 0..255 forward (R13 machinery verbatim, NPH=128 pairs, 191
// steps). Wave 1: rows 511..256 backward = a forward DP in reversed coords
// (x'_i = x[511-i], y'_j = y[511-j]):
//   Gb'[i',j'] = A'*Gb'[i'-1,j'-1] + B'*Gb'[i'-1,j'] + C'*Gb'[i',j'-1]
//   A'(i',j') = e^{2-(x'_{i'-1}-y'_{j'-1})^2}
//   B' gate dx'_{i'}*(x'_{i'-1}-y'_{j'}) < 0, val e^{-dx'^2}+e^{-(x'_{i'-1}-y'_{j'})^2}
//   C' gate dy'_{j'}*(x'_{i'}-y'_{j'-1}) > 0, val e^{-dy'^2}+e^{-(x'_{i'}-y'_{j'-1})^2}
// exp sharing: B-exp(k) = A-exp(k+1) (same row), C-exp(row r) = A-exp(row r+1)
// -> 18 exps/step (9/new row, 9-wide with one col of lookahead), A-exp row
// carry across steps. Seed Gb'[0,0]=1 via A'(0,0):=1, dv0:=1.
// No inter-wave traffic during loops; one barrier + O(512) log-space combine
// (per-lane 2^kacc scales folded into true logs; LSE over the 512 seam terms).

#define TT 512
#define BATCH 64
#define G 8                      // cols per lane
#define NPH 128                  // row-pairs per half; steps/wave = 191
#define C1F 1.2011224087864498f  // sqrt(log2 e)
#define C2F 2.8853900817779268f  // 2*log2 e
#define K2F 0.13533528323661270f // e^-2
#define LN2F 0.69314718055994531f
#define NEG_BIG (-1e30f)

#if __has_builtin(__builtin_amdgcn_exp2f)
#define EXP2F(x) __builtin_amdgcn_exp2f(x)
#else
#define EXP2F(x) __expf((x) * LN2F)
#endif

typedef float v2f __attribute__((ext_vector_type(2)));

__device__ __forceinline__ float dpp_shr1_f(float src, float old) {
  return __int_as_float(__builtin_amdgcn_update_dpp(
      __float_as_int(old), __float_as_int(src), 0x138, 0xF, 0xF, false));
}
__device__ __forceinline__ int dpp_shr1_i(int src, int old) {
  return __builtin_amdgcn_update_dpp(old, src, 0x138, 0xF, 0xF, false);
}

__global__ __launch_bounds__(128, 1) void msm_kernel(const float* __restrict__ x,
                                                     const float* __restrict__ y,
                                                     float* __restrict__ ws) {
  const int b = blockIdx.x;
  const int tid = threadIdx.x;
  const int wv = tid >> 6;
  const int j = tid & 63;
  const float* xb = x + b * TT;
  const float* yb = y + b * TT;

  __shared__ float2 FXC[NPH], FDX[NPH], FEX[NPH];   // fwd rows 0..255
  __shared__ float2 BXA[NPH], BDX[NPH], BEX[NPH];   // bwd primed rows 0..255
  __shared__ float LF[TT], LG[TT], TERMS[TT];

  // ---- staging: each wave stages its own half (4 rows / 2 pairs per lane) ----
  if (wv == 0) {
    float4 xq = ((const float4*)xb)[j];            // x[4j..4j+3]
    float rx[4] = {xq.x, xq.y, xq.z, xq.w};
    float prev = (j > 0) ? xb[4 * j - 1] : 0.0f;
    float cc[4], dd[4], ee[4];
#pragma unroll
    for (int k = 0; k < 4; ++k) {
      float dx = rx[k] - prev;                     // row 0's dx unused
      prev = rx[k];
      cc[k] = rx[k] * C1F;
      dd[k] = dx;
      ee[k] = __expf(-dx * dx);
    }
    FXC[2 * j] = make_float2(cc[0], cc[1]);
    FXC[2 * j + 1] = make_float2(cc[2], cc[3]);
    FDX[2 * j] = make_float2(dd[0], dd[1]);
    FDX[2 * j + 1] = make_float2(dd[2], dd[3]);
    FEX[2 * j] = make_float2(ee[0], ee[1]);
    FEX[2 * j + 1] = make_float2(ee[2], ee[3]);
  } else {
    float cc[4], dd[4], ee[4];
#pragma unroll
    for (int k = 0; k < 4; ++k) {
      int rp = 4 * j + k;                          // primed row
      int i1 = 512 - rp; if (i1 > 511) i1 = 511;   // x'_{r-1} source (r=0 unused)
      int i2 = 511 - rp;                           // x'_r
      float xa = xb[i1];
      float dxp = xb[i2] - xa;                     // dx'_r (r=0: 0, unused)
      cc[k] = xa * C1F;
      dd[k] = dxp;
      ee[k] = __expf(-dxp * dxp);
    }
    BXA[2 * j] = make_float2(cc[0], cc[1]);
    BXA[2 * j + 1] = make_float2(cc[2], cc[3]);
    BDX[2 * j] = make_float2(dd[0], dd[1]);
    BDX[2 * j + 1] = make_float2(dd[2], dd[3]);
    BEX[2 * j] = make_float2(ee[0], ee[1]);
    BEX[2 * j + 1] = make_float2(ee[2], ee[3]);
  }
  __syncthreads();

  float EpF[G];
#pragma unroll
  for (int k = 0; k < G; ++k) EpF[k] = 0.0f;
  int kaccF = 0;

  if (wv == 0) {
    // ================= FORWARD (R13 machinery, NPH=128) =================
    float yc[G], dyS[G], edy2[G];
    {
      const float4* yv = (const float4*)yb;
      float4 a0 = yv[j * 2], a1 = yv[j * 2 + 1];
      float ry[G] = {a0.x, a0.y, a0.z, a0.w, a1.x, a1.y, a1.z, a1.w};
      float prev = (j > 0) ? yb[8 * j - 1] : 0.0f;
#pragma unroll
      for (int k = 0; k < G; ++k) {
        float dy = ry[k] - prev;
        prev = ry[k];
        yc[k] = ry[k] * C1F;
        dyS[k] = dy;
        edy2[k] = __expf(-dy * dy);
      }
    }
    float dc0 = 0.0f, dc1 = 0.0f, dc2 = 0.0f;
    float2 rdEx = FXC[0], rdEd = FDX[0], rdEe = FEX[0];
    float2 rdOx, rdOd, rdOe;

    auto fstep = [&](int t, auto phc, float2& xcU, float2& dxU, float2& exU,
                     float2& xcL, float2& dxL, float2& exL) {
      constexpr int PH = decltype(phc)::value;
      {
        int pn = t + 2 - j;
        pn = (pn < 0) ? 0 : ((pn > NPH - 1) ? NPH - 1 : pn);
        xcL = FXC[pn]; dxL = FDX[pn]; exL = FEX[pn];
      }
      float r0 = dpp_shr1_f(dc0, 0.0f);
      float r1 = dpp_shr1_f(dc1, 0.0f);
      float r2 = dpp_shr1_f(dc2, 0.0f);
      int k_in = dpp_shr1_i(kaccF, kaccF);
      const int p = t - j;
      if (PH == 0) {
        if (t == 0 && j == 0) r0 = K2F;            // seed F[-1,-1] = e^{-2}
      }
      bool act = true;
      int kacc_e = kaccF;
      if (PH == 0) { act = (p >= 0); kacc_e = (p == 0) ? k_in : kaccF; }
      else if (PH == 2) { act = (p < NPH); }
      const int knew = (k_in > kacc_e) ? k_in : kacc_e;
      const float mMe = ldexpf(1.0f, kacc_e - knew);
      const float mIn = ldexpf(1.0f, k_in - knew);
      const float dv0 = r0 * mIn, dv1 = r1 * mIn, dv2 = r2 * mIn;
      const float nd0 = dc2 * mMe;
      float u[G];
#pragma unroll
      for (int k = 0; k < G; ++k) u[k] = EpF[k] * mMe;

      const v2f xcp = {xcU.x, xcU.y};
      const v2f dxp = {dxU.x, dxU.y};
      const v2f exv = {exU.x, exU.y};
      v2f Aw[G], Bw[G], Cw[G];
#define WCELL(kk)                                                       \
      {                                                                 \
        v2f s1 = xcp - yc[kk];                                          \
        v2f arg = C2F - s1 * s1;                                        \
        v2f A;                                                          \
        A.x = EXP2F(arg.x);                                             \
        A.y = EXP2F(arg.y);                                             \
        v2f Bs = A * K2F + exv;                                         \
        v2f Cs = A * K2F + edy2[kk];                                    \
        v2f gu = dxp * s1;                                              \
        v2f gl = dyS[kk] * s1;                                          \
        Aw[kk] = A;                                                     \
        Bw[kk].x = (gu.x > 0.0f) ? Bs.x : 1.0f;                         \
        Bw[kk].y = (gu.y > 0.0f) ? Bs.y : 1.0f;                         \
        Cw[kk].x = (gl.x < 0.0f) ? Cs.x : 1.0f;                         \
        Cw[kk].y = (gl.y < 0.0f) ? Cs.y : 1.0f;                         \
      }
      WCELL(0) WCELL(1) WCELL(2)
      float T0[G], T1[G];
#pragma unroll
      for (int k = 0; k < G; ++k) {
        if (k + 3 < G) WCELL(k + 3)
        __builtin_amdgcn_sched_barrier(0);
        float da = (k == 0) ? dv0 : u[k - 1];
        float pa = __fmaf_rn(da, Aw[k].x, u[k] * Bw[k].x);
        T0[k] = __fmaf_rn((k == 0) ? dv1 : T0[k - 1], Cw[k].x, pa);
        float db = (k == 0) ? dv1 : T0[k - 1];
        float pb = __fmaf_rn(db, Aw[k].y, T0[k] * Bw[k].y);
        T1[k] = __fmaf_rn((k == 0) ? dv2 : T1[k - 1], Cw[k].y, pb);
      }
#undef WCELL
      const float ndc1 = T0[G - 1];
      float m0 = fmaxf(fmaxf(T1[0], T1[1]), T1[2]);
      float m1 = fmaxf(fmaxf(T1[3], T1[4]), T1[5]);
      float m2 = fmaxf(fmaxf(T1[6], T1[7]), nd0);
      float vmax = fmaxf(fmaxf(m0, m1), fmaxf(m2, ndc1));
      unsigned ue = (__float_as_uint(vmax) >> 23) & 0xFFu;
      int e = (int)ue - 126;
      float sc = ldexpf(1.0f, -e);
      if (PH == 1) {
#pragma unroll
        for (int k = 0; k < G; ++k) EpF[k] = T1[k] * sc;
        dc0 = nd0 * sc; dc1 = ndc1 * sc; dc2 = EpF[G - 1];
        kaccF = knew + e;
      } else {
#pragma unroll
        for (int k = 0; k < G; ++k) EpF[k] = act ? T1[k] * sc : EpF[k];
        dc0 = act ? nd0 * sc : dc0;
        dc1 = act ? ndc1 * sc : dc1;
        dc2 = act ? EpF[G - 1] : dc2;
        kaccF = act ? knew + e : kaccF;
      }
    };
    std::integral_constant<int, 0> P0;
    std::integral_constant<int, 1> P1;
    std::integral_constant<int, 2> P2;
    for (int t = 0; t < 64; t += 2) {
      fstep(t, P0, rdEx, rdEd, rdEe, rdOx, rdOd, rdOe);
      fstep(t + 1, P0, rdOx, rdOd, rdOe, rdEx, rdEd, rdEe);
    }
    for (int t = 64; t < 128; t += 2) {
      fstep(t, P1, rdEx, rdEd, rdEe, rdOx, rdOd, rdOe);
      fstep(t + 1, P1, rdOx, rdOd, rdOe, rdEx, rdEd, rdEe);
    }
    for (int t = 128; t < 192; t += 2) {           // t=191 inert
      fstep(t, P2, rdEx, rdEd, rdEe, rdOx, rdOd, rdOe);
      fstep(t + 1, P2, rdOx, rdOd, rdOe, rdEx, rdEd, rdEe);
    }
    // publish log E[255, col] (true scale; e^{i+j} factor removed)
#pragma unroll
    for (int k = 0; k < G; ++k) {
      float le = (EpF[k] > 0.0f) ? __logf(EpF[k]) : NEG_BIG;
      LF[8 * j + k] = le + (float)kaccF * LN2F - (float)(255 + 8 * j + k);
    }
  } else {
    // ================= BACKWARD (mirrored forward) =================
    float ycP[G + 1], dyP[G], edy2P[G];
    {
#pragma unroll
      for (int k = 0; k <= G; ++k) {
        int idx = 512 - 8 * j - k; if (idx > 511) idx = 511;
        ycP[k] = yb[idx] * C1F;                    // y'_{j'-1}*C1, j'=8j+k
      }
#pragma unroll
      for (int k = 0; k < G; ++k) {
        int ia = 511 - 8 * j - k;
        int ib = 512 - 8 * j - k; if (ib > 511) ib = 511;
        float d = yb[ia] - yb[ib];                 // dy'_{8j+k} (j=0,k=0 unused)
        dyP[k] = d;
        edy2P[k] = __expf(-d * d);
      }
    }
    float dc0 = 0.0f, dc1 = 0.0f, dc2 = 0.0f;
    float sA[G + 1], eA[G + 1];                    // carry: A-exps of row 2p
    {
      float xa0 = BXA[0].x;
#pragma unroll
      for (int k = 0; k <= G; ++k) {
        float s = xa0 - ycP[k];
        sA[k] = s;
        eA[k] = EXP2F(C2F - s * s);                // e^{2-dA^2}
      }
    }
    float2 cxA = BXA[0], cdx = BDX[0], cex = BEX[0];

    auto bstep = [&](int t, auto phc) {
      constexpr int PH = decltype(phc)::value;
      const int p = t - j;
      int pn = t + 1 - j;
      pn = (pn < 0) ? 0 : ((pn > NPH - 1) ? NPH - 1 : pn);
      float2 nxA = BXA[pn], ndx = BDX[pn], nex = BEX[pn];
      float r0 = dpp_shr1_f(dc0, 0.0f);
      float r1 = dpp_shr1_f(dc1, 0.0f);
      float r2 = dpp_shr1_f(dc2, 0.0f);
      int k_in = dpp_shr1_i(kaccF, kaccF);
      const bool seed = (PH == 0) && (t == 0) && (j == 0);
      if (seed) r0 = 1.0f;                         // Gb'[0,0] = 1 (with A:=1)
      bool act = true;
      int kacc_e = kaccF;
      if (PH == 0) { act = (p >= 0); kacc_e = (p == 0) ? k_in : kaccF; }
      else if (PH == 2) { act = (p < NPH); }
      const int knew = (k_in > kacc_e) ? k_in : kacc_e;
      const float mMe = ldexpf(1.0f, kacc_e - knew);
      const float mIn = ldexpf(1.0f, k_in - knew);
      const float dv0 = r0 * mIn, dv1 = r1 * mIn, dv2 = r2 * mIn;
      const float nd0 = dc2 * mMe;
      float u[G];
#pragma unroll
      for (int k = 0; k < G; ++k) u[k] = EpF[k] * mMe;

      // A-exps for row 2p+1 (in-pair) and row 2p+2 (next carry)
      float sB[G + 1], eB[G + 1], sN[G + 1], eN[G + 1];
      const float xab = cxA.y, xan = nxA.x;
#pragma unroll
      for (int k = 0; k <= G; ++k) {
        float s = xab - ycP[k];
        sB[k] = s;
        eB[k] = EXP2F(C2F - s * s);
      }
#pragma unroll
      for (int k = 0; k <= G; ++k) {
        float s = xan - ycP[k];
        sN[k] = s;
        eN[k] = EXP2F(C2F - s * s);
      }
      const float dxa = cdx.x, dxb = cdx.y, exa = cex.x, exb = cex.y;
      float Aa[G], Ba[G], Ca[G], Ab[G], Bb[G], Cb[G];
#pragma unroll
      for (int k = 0; k < G; ++k) {
        Aa[k] = eA[k];
        Ba[k] = (dxa * sA[k + 1] < 0.0f) ? __fmaf_rn(eA[k + 1], K2F, exa) : 1.0f;
        Ca[k] = (dyP[k] * sB[k] > 0.0f) ? __fmaf_rn(eB[k], K2F, edy2P[k]) : 1.0f;
        Ab[k] = eB[k];
        Bb[k] = (dxb * sB[k + 1] < 0.0f) ? __fmaf_rn(eB[k + 1], K2F, exb) : 1.0f;
        Cb[k] = (dyP[k] * sN[k] > 0.0f) ? __fmaf_rn(eN[k], K2F, edy2P[k]) : 1.0f;
      }
      if (seed) Aa[0] = 1.0f;
      __builtin_amdgcn_sched_barrier(0);
      float T0[G], T1[G];
#pragma unroll
      for (int k = 0; k < G; ++k) {
        float da = (k == 0) ? dv0 : u[k - 1];
        float pa = __fmaf_rn(da, Aa[k], u[k] * Ba[k]);
        T0[k] = __fmaf_rn((k == 0) ? dv1 : T0[k - 1], Ca[k], pa);
        float db = (k == 0) ? dv1 : T0[k - 1];
        float pb = __fmaf_rn(db, Ab[k], T0[k] * Bb[k]);
        T1[k] = __fmaf_rn((k == 0) ? dv2 : T1[k - 1], Cb[k], pb);
      }
      const float ndc1 = T0[G - 1];
      float m0 = fmaxf(fmaxf(T1[0], T1[1]), T1[2]);
      float m1 = fmaxf(fmaxf(T1[3], T1[4]), T1[5]);
      float m2 = fmaxf(fmaxf(T1[6], T1[7]), nd0);
      float vmax = fmaxf(fmaxf(m0, m1), fmaxf(m2, ndc1));
      unsigned ue = (__float_as_uint(vmax) >> 23) & 0xFFu;
      int e = (int)ue - 126;
      float sc = ldexpf(1.0f, -e);
      if (PH == 1) {
#pragma unroll
        for (int k = 0; k < G; ++k) EpF[k] = T1[k] * sc;
        dc0 = nd0 * sc; dc1 = ndc1 * sc; dc2 = EpF[G - 1];
        kaccF = knew + e;
      } else {
#pragma unroll
        for (int k = 0; k < G; ++k) EpF[k] = act ? T1[k] * sc : EpF[k];
        dc0 = act ? nd0 * sc : dc0;
        dc1 = act ? ndc1 * sc : dc1;
        dc2 = act ? EpF[G - 1] : dc2;
        kaccF = act ? knew + e : kaccF;
      }
      // rotate carries/banks (unconditional: ramp-in lanes keep row 0)
#pragma unroll
      for (int k = 0; k <= G; ++k) { sA[k] = sN[k]; eA[k] = eN[k]; }
      cxA = nxA; cdx = ndx; cex = nex;
    };
    std::integral_constant<int, 0> P0;
    std::integral_constant<int, 1> P1;
    std::integral_constant<int, 2> P2;
    for (int t = 0; t < 64; ++t) bstep(t, P0);
    for (int t = 64; t < 128; ++t) bstep(t, P1);
    for (int t = 128; t < 191; ++t) bstep(t, P2);
    // publish log Gb[256, col]; lane owns primed cols j'=8j..8j+7 (col=511-j')
#pragma unroll
    for (int k = 0; k < G; ++k) {
      float le = (EpF[k] > 0.0f) ? __logf(EpF[k]) : NEG_BIG;
      LG[511 - (8 * j + k)] = le + (float)kaccF * LN2F - (float)(255 + 8 * j + k);
    }
  }
  __syncthreads();

  // ---- combine: term_j = LG[j] + log(Em_j e^{LF[j-1]} + Wu_j e^{LF[j]}) ----
  {
    const float sx = xb[256];
    const float dxs = sx - xb[255];
    const float ex2s = __expf(-dxs * dxs);
#pragma unroll
    for (int c = 0; c < 4; ++c) {
      int jj = 4 * tid + c;
      float d = sx - yb[jj];
      float m2 = d * d;
      float lw = (dxs * d > 0.0f) ? __logf(ex2s + __expf(-m2)) : 0.0f;
      float t1 = ((jj > 0) ? LF[jj - 1] : NEG_BIG) - m2;
      float t2 = LF[jj] - 1.0f + lw;
      float mt = fmaxf(t1, t2);
      float term = NEG_BIG;
      if (mt > -1e29f)
        term = LG[jj] + mt + __logf(__expf(t1 - mt) + __expf(t2 - mt));
      TERMS[jj] = term;
    }
  }
  __syncthreads();
  if (wv == 0) {
    float v[8];
    float M = NEG_BIG;
#pragma unroll
    for (int i = 0; i < 8; ++i) {
      v[i] = TERMS[8 * j + i];
      M = fmaxf(M, v[i]);
    }
#pragma unroll
    for (int off = 1; off < 64; off <<= 1) M = fmaxf(M, __shfl_xor(M, off));
    float S = 0.0f;
#pragma unroll
    for (int i = 0; i < 8; ++i) S += __expf(v[i] - M);
#pragma unroll
    for (int off = 1; off < 64; off <<= 1) S += __shfl_xor(S, off);
    if (j == 0) ws[b] = -(M + __logf(S));
  }
}

__global__ __launch_bounds__(64) void reduce_kernel(const float* __restrict__ ws,
                                                    float* __restrict__ out) {
  float v = ws[threadIdx.x];
#pragma unroll
  for (int off = 32; off > 0; off >>= 1) v += __shfl_down(v, off);
  if (threadIdx.x == 0) out[0] = v * (1.0f / BATCH);
}

extern "C" void kernel_launch(void* const* d_in, const int* in_sizes, int n_in,
                              void* d_out, int out_size, void* d_ws, size_t ws_size,
                              hipStream_t stream) {
  const float* x = (const float*)d_in[0];
  const float* y = (const float*)d_in[1];
  float* ws = (float*)d_ws;
  float* out = (float*)d_out;
  msm_kernel<<<BATCH, 128, 0, stream>>>(x, y, ws);
  reduce_kernel<<<1, 64, 0, stream>>>(ws, out);
}

// Round 16
// 158.234 us; speedup vs baseline: 4.4720x; 1.0546x over previous
//
#include <hip/hip_runtime.h>
#include <math.h>
#include <type_traits>

// SoftMSM loss on MI355X — round 15.
// Bidirectional meet-in-the-middle (R14, verified absmax 0.5) with the
// BACKWARD wave slimmed to fwd's per-step cost:
//   - the two new 9-entry exp windows per step (rows 2p+1, 2p+2) packed as
//     v2f -> v_pk math for args (was scalar: ~72 -> ~36 cyc)
//   - ping-pong window banks across unroll-2 (kills the 9x2 v_mov rotation)
//   - R13-style sliding-window interleave with sched_barrier(0) per column
// Fwd wave, seam combine, reduce: verbatim R14.
//
//   E_total = sum_j Gb[256,j] * ( Em(256,j)*E[255,j-1] + Wu(256,j)*E[255,j] )
// Bwd DP in reversed coords (x'_i = x[511-i], y'_j = y[511-j]):
//   Gb'[i',j'] = A'*Gb'[i'-1,j'-1] + B'*Gb'[i'-1,j'] + C'*Gb'[i',j'-1]
//   A'(i',j') = e^{2-(X~_{i'}-Y~_{j'})^2},  X~_r = x[512-r], Y~_c = y[512-c]
//   B' gate dx'_i'*(X~_i'-Y~_{j'+1}) < 0, val e^{-dx'^2}+e^{-(X~_i'-Y~_{j'+1})^2}
//   C' gate dy'_j'*(X~_{i'+1}-Y~_{j'}) > 0, val e^{-dy'^2}+e^{-(X~_{i'+1}-Y~_{j'})^2}
// (window entry m of row r = exp(2-(X~_r - Y~_{j'base+m-1})^2); B uses m+1,
//  C of row r uses row r+1's window — all verified in R14.)

#define TT 512
#define BATCH 64
#define G 8
#define NPH 128                  // row-pairs per half; steps/wave = 191
#define C1F 1.2011224087864498f  // sqrt(log2 e)
#define C2F 2.8853900817779268f  // 2*log2 e
#define K2F 0.13533528323661270f // e^-2
#define LN2F 0.69314718055994531f
#define NEG_BIG (-1e30f)

#if __has_builtin(__builtin_amdgcn_exp2f)
#define EXP2F(x) __builtin_amdgcn_exp2f(x)
#else
#define EXP2F(x) __expf((x) * LN2F)
#endif

typedef float v2f __attribute__((ext_vector_type(2)));

__device__ __forceinline__ float dpp_shr1_f(float src, float old) {
  return __int_as_float(__builtin_amdgcn_update_dpp(
      __float_as_int(old), __float_as_int(src), 0x138, 0xF, 0xF, false));
}
__device__ __forceinline__ int dpp_shr1_i(int src, int old) {
  return __builtin_amdgcn_update_dpp(old, src, 0x138, 0xF, 0xF, false);
}

__global__ __launch_bounds__(128, 1) void msm_kernel(const float* __restrict__ x,
                                                     const float* __restrict__ y,
                                                     float* __restrict__ ws) {
  const int b = blockIdx.x;
  const int tid = threadIdx.x;
  const int wv = tid >> 6;
  const int j = tid & 63;
  const float* xb = x + b * TT;
  const float* yb = y + b * TT;

  __shared__ float2 FXC[NPH], FDX[NPH], FEX[NPH];   // fwd rows 0..255
  __shared__ float2 BXA[NPH], BDX[NPH], BEX[NPH];   // bwd primed rows 0..255
  __shared__ float LF[TT], LG[TT], TERMS[TT];

  // ---- staging (R14 verbatim) ----
  if (wv == 0) {
    float4 xq = ((const float4*)xb)[j];
    float rx[4] = {xq.x, xq.y, xq.z, xq.w};
    float prev = (j > 0) ? xb[4 * j - 1] : 0.0f;
    float cc[4], dd[4], ee[4];
#pragma unroll
    for (int k = 0; k < 4; ++k) {
      float dx = rx[k] - prev;
      prev = rx[k];
      cc[k] = rx[k] * C1F;
      dd[k] = dx;
      ee[k] = __expf(-dx * dx);
    }
    FXC[2 * j] = make_float2(cc[0], cc[1]);
    FXC[2 * j + 1] = make_float2(cc[2], cc[3]);
    FDX[2 * j] = make_float2(dd[0], dd[1]);
    FDX[2 * j + 1] = make_float2(dd[2], dd[3]);
    FEX[2 * j] = make_float2(ee[0], ee[1]);
    FEX[2 * j + 1] = make_float2(ee[2], ee[3]);
  } else {
    float cc[4], dd[4], ee[4];
#pragma unroll
    for (int k = 0; k < 4; ++k) {
      int rp = 4 * j + k;
      int i1 = 512 - rp; if (i1 > 511) i1 = 511;
      int i2 = 511 - rp;
      float xa = xb[i1];
      float dxp = xb[i2] - xa;
      cc[k] = xa * C1F;
      dd[k] = dxp;
      ee[k] = __expf(-dxp * dxp);
    }
    BXA[2 * j] = make_float2(cc[0], cc[1]);
    BXA[2 * j + 1] = make_float2(cc[2], cc[3]);
    BDX[2 * j] = make_float2(dd[0], dd[1]);
    BDX[2 * j + 1] = make_float2(dd[2], dd[3]);
    BEX[2 * j] = make_float2(ee[0], ee[1]);
    BEX[2 * j + 1] = make_float2(ee[2], ee[3]);
  }
  __syncthreads();

  float EpF[G];
#pragma unroll
  for (int k = 0; k < G; ++k) EpF[k] = 0.0f;
  int kaccF = 0;

  if (wv == 0) {
    // ================= FORWARD (R14 verbatim) =================
    float yc[G], dyS[G], edy2[G];
    {
      const float4* yv = (const float4*)yb;
      float4 a0 = yv[j * 2], a1 = yv[j * 2 + 1];
      float ry[G] = {a0.x, a0.y, a0.z, a0.w, a1.x, a1.y, a1.z, a1.w};
      float prev = (j > 0) ? yb[8 * j - 1] : 0.0f;
#pragma unroll
      for (int k = 0; k < G; ++k) {
        float dy = ry[k] - prev;
        prev = ry[k];
        yc[k] = ry[k] * C1F;
        dyS[k] = dy;
        edy2[k] = __expf(-dy * dy);
      }
    }
    float dc0 = 0.0f, dc1 = 0.0f, dc2 = 0.0f;
    float2 rdEx = FXC[0], rdEd = FDX[0], rdEe = FEX[0];
    float2 rdOx, rdOd, rdOe;

    auto fstep = [&](int t, auto phc, float2& xcU, float2& dxU, float2& exU,
                     float2& xcL, float2& dxL, float2& exL) {
      constexpr int PH = decltype(phc)::value;
      {
        int pn = t + 2 - j;
        pn = (pn < 0) ? 0 : ((pn > NPH - 1) ? NPH - 1 : pn);
        xcL = FXC[pn]; dxL = FDX[pn]; exL = FEX[pn];
      }
      float r0 = dpp_shr1_f(dc0, 0.0f);
      float r1 = dpp_shr1_f(dc1, 0.0f);
      float r2 = dpp_shr1_f(dc2, 0.0f);
      int k_in = dpp_shr1_i(kaccF, kaccF);
      const int p = t - j;
      if (PH == 0) {
        if (t == 0 && j == 0) r0 = K2F;
      }
      bool act = true;
      int kacc_e = kaccF;
      if (PH == 0) { act = (p >= 0); kacc_e = (p == 0) ? k_in : kaccF; }
      else if (PH == 2) { act = (p < NPH); }
      const int knew = (k_in > kacc_e) ? k_in : kacc_e;
      const float mMe = ldexpf(1.0f, kacc_e - knew);
      const float mIn = ldexpf(1.0f, k_in - knew);
      const float dv0 = r0 * mIn, dv1 = r1 * mIn, dv2 = r2 * mIn;
      const float nd0 = dc2 * mMe;
      float u[G];
#pragma unroll
      for (int k = 0; k < G; ++k) u[k] = EpF[k] * mMe;

      const v2f xcp = {xcU.x, xcU.y};
      const v2f dxp = {dxU.x, dxU.y};
      const v2f exv = {exU.x, exU.y};
      v2f Aw[G], Bw[G], Cw[G];
#define WCELL(kk)                                                       \
      {                                                                 \
        v2f s1 = xcp - yc[kk];                                          \
        v2f arg = C2F - s1 * s1;                                        \
        v2f A;                                                          \
        A.x = EXP2F(arg.x);                                             \
        A.y = EXP2F(arg.y);                                             \
        v2f Bs = A * K2F + exv;                                         \
        v2f Cs = A * K2F + edy2[kk];                                    \
        v2f gu = dxp * s1;                                              \
        v2f gl = dyS[kk] * s1;                                          \
        Aw[kk] = A;                                                     \
        Bw[kk].x = (gu.x > 0.0f) ? Bs.x : 1.0f;                         \
        Bw[kk].y = (gu.y > 0.0f) ? Bs.y : 1.0f;                         \
        Cw[kk].x = (gl.x < 0.0f) ? Cs.x : 1.0f;                         \
        Cw[kk].y = (gl.y < 0.0f) ? Cs.y : 1.0f;                         \
      }
      WCELL(0) WCELL(1) WCELL(2)
      float T0[G], T1[G];
#pragma unroll
      for (int k = 0; k < G; ++k) {
        if (k + 3 < G) WCELL(k + 3)
        __builtin_amdgcn_sched_barrier(0);
        float da = (k == 0) ? dv0 : u[k - 1];
        float pa = __fmaf_rn(da, Aw[k].x, u[k] * Bw[k].x);
        T0[k] = __fmaf_rn((k == 0) ? dv1 : T0[k - 1], Cw[k].x, pa);
        float db = (k == 0) ? dv1 : T0[k - 1];
        float pb = __fmaf_rn(db, Aw[k].y, T0[k] * Bw[k].y);
        T1[k] = __fmaf_rn((k == 0) ? dv2 : T1[k - 1], Cw[k].y, pb);
      }
#undef WCELL
      const float ndc1 = T0[G - 1];
      float m0 = fmaxf(fmaxf(T1[0], T1[1]), T1[2]);
      float m1 = fmaxf(fmaxf(T1[3], T1[4]), T1[5]);
      float m2 = fmaxf(fmaxf(T1[6], T1[7]), nd0);
      float vmax = fmaxf(fmaxf(m0, m1), fmaxf(m2, ndc1));
      unsigned ue = (__float_as_uint(vmax) >> 23) & 0xFFu;
      int e = (int)ue - 126;
      float sc = ldexpf(1.0f, -e);
      if (PH == 1) {
#pragma unroll
        for (int k = 0; k < G; ++k) EpF[k] = T1[k] * sc;
        dc0 = nd0 * sc; dc1 = ndc1 * sc; dc2 = EpF[G - 1];
        kaccF = knew + e;
      } else {
#pragma unroll
        for (int k = 0; k < G; ++k) EpF[k] = act ? T1[k] * sc : EpF[k];
        dc0 = act ? nd0 * sc : dc0;
        dc1 = act ? ndc1 * sc : dc1;
        dc2 = act ? EpF[G - 1] : dc2;
        kaccF = act ? knew + e : kaccF;
      }
    };
    std::integral_constant<int, 0> P0;
    std::integral_constant<int, 1> P1;
    std::integral_constant<int, 2> P2;
    for (int t = 0; t < 64; t += 2) {
      fstep(t, P0, rdEx, rdEd, rdEe, rdOx, rdOd, rdOe);
      fstep(t + 1, P0, rdOx, rdOd, rdOe, rdEx, rdEd, rdEe);
    }
    for (int t = 64; t < 128; t += 2) {
      fstep(t, P1, rdEx, rdEd, rdEe, rdOx, rdOd, rdOe);
      fstep(t + 1, P1, rdOx, rdOd, rdOe, rdEx, rdEd, rdEe);
    }
    for (int t = 128; t < 192; t += 2) {
      fstep(t, P2, rdEx, rdEd, rdEe, rdOx, rdOd, rdOe);
      fstep(t + 1, P2, rdOx, rdOd, rdOe, rdEx, rdEd, rdEe);
    }
#pragma unroll
    for (int k = 0; k < G; ++k) {
      float le = (EpF[k] > 0.0f) ? __logf(EpF[k]) : NEG_BIG;
      LF[8 * j + k] = le + (float)kaccF * LN2F - (float)(255 + 8 * j + k);
    }
  } else {
    // ============ BACKWARD (packed windows + ping-pong banks) ============
    float ycP[G + 1], dyP[G], edy2P[G];
    {
#pragma unroll
      for (int k = 0; k <= G; ++k) {
        int idx = 512 - 8 * j - k; if (idx > 511) idx = 511;
        ycP[k] = yb[idx] * C1F;
      }
#pragma unroll
      for (int k = 0; k < G; ++k) {
        int ia = 511 - 8 * j - k;
        int ib = 512 - 8 * j - k; if (ib > 511) ib = 511;
        float d = yb[ia] - yb[ib];
        dyP[k] = d;
        edy2P[k] = __expf(-d * d);
      }
    }
    float dc0 = 0.0f, dc1 = 0.0f, dc2 = 0.0f;
    // ping-pong window banks: {s,e}[G+1] each
    float sBk0[G + 1], eBk0[G + 1], sBk1[G + 1], eBk1[G + 1];
    {
      float xa0 = BXA[0].x;
#pragma unroll
      for (int k = 0; k <= G; ++k) {
        float s = xa0 - ycP[k];
        sBk0[k] = s;
        eBk0[k] = EXP2F(C2F - s * s);
      }
    }
    float2 cxA = BXA[0], cdx = BDX[0], cex = BEX[0];

    // in-bank (sU,eU) = window of row 2p; out-bank gets row 2p+2's window
    auto bstep = [&](int t, auto phc, float (&sU)[G + 1], float (&eU)[G + 1],
                     float (&sO)[G + 1], float (&eO)[G + 1]) {
      constexpr int PH = decltype(phc)::value;
      const int p = t - j;
      int pn = t + 1 - j;
      pn = (pn < 0) ? 0 : ((pn > NPH - 1) ? NPH - 1 : pn);
      float2 nxA = BXA[pn], ndx = BDX[pn], nex = BEX[pn];
      float r0 = dpp_shr1_f(dc0, 0.0f);
      float r1 = dpp_shr1_f(dc1, 0.0f);
      float r2 = dpp_shr1_f(dc2, 0.0f);
      int k_in = dpp_shr1_i(kaccF, kaccF);
      const bool seed = (PH == 0) && (t == 0) && (j == 0);
      if (seed) r0 = 1.0f;                         // Gb'[0,0] = 1 (with A:=1)
      bool act = true;
      int kacc_e = kaccF;
      if (PH == 0) { act = (p >= 0); kacc_e = (p == 0) ? k_in : kaccF; }
      else if (PH == 2) { act = (p < NPH); }
      const int knew = (k_in > kacc_e) ? k_in : kacc_e;
      const float mMe = ldexpf(1.0f, kacc_e - knew);
      const float mIn = ldexpf(1.0f, k_in - knew);
      const float dv0 = r0 * mIn, dv1 = r1 * mIn, dv2 = r2 * mIn;
      const float nd0 = dc2 * mMe;
      float u[G];
#pragma unroll
      for (int k = 0; k < G; ++k) u[k] = EpF[k] * mMe;

      // packed window build: rows 2p+1 (V, local) and 2p+2 (W -> out bank)
      const v2f xbn = {cxA.y, nxA.x};
      float sV[G + 1], eV[G + 1];
#define BWIN(mm)                                                        \
      {                                                                 \
        v2f sw = xbn - ycP[mm];                                         \
        v2f arg = C2F - sw * sw;                                        \
        sV[mm] = sw.x;  eV[mm] = EXP2F(arg.x);                          \
        sO[mm] = sw.y;  eO[mm] = EXP2F(arg.y);                          \
      }
      BWIN(0) BWIN(1) BWIN(2) BWIN(3) BWIN(4)
      const float dxa = cdx.x, dxb = cdx.y, exa = cex.x, exb = cex.y;
      float T0[G], T1[G];
#pragma unroll
      for (int k = 0; k < G; ++k) {
        if (k + 5 <= G) BWIN(k + 5)
        __builtin_amdgcn_sched_barrier(0);
        float Aa = eU[k];
        if (seed && k == 0) Aa = 1.0f;
        float Ba = (dxa * sU[k + 1] < 0.0f) ? __fmaf_rn(eU[k + 1], K2F, exa) : 1.0f;
        float Ca = (dyP[k] * sV[k] > 0.0f) ? __fmaf_rn(eV[k], K2F, edy2P[k]) : 1.0f;
        float Ab = eV[k];
        float Bb = (dxb * sV[k + 1] < 0.0f) ? __fmaf_rn(eV[k + 1], K2F, exb) : 1.0f;
        float Cb = (dyP[k] * sO[k] > 0.0f) ? __fmaf_rn(eO[k], K2F, edy2P[k]) : 1.0f;
        float da = (k == 0) ? dv0 : u[k - 1];
        float pa = __fmaf_rn(da, Aa, u[k] * Ba);
        T0[k] = __fmaf_rn((k == 0) ? dv1 : T0[k - 1], Ca, pa);
        float db = (k == 0) ? dv1 : T0[k - 1];
        float pb = __fmaf_rn(db, Ab, T0[k] * Bb);
        T1[k] = __fmaf_rn((k == 0) ? dv2 : T1[k - 1], Cb, pb);
      }
#undef BWIN
      const float ndc1 = T0[G - 1];
      float m0 = fmaxf(fmaxf(T1[0], T1[1]), T1[2]);
      float m1 = fmaxf(fmaxf(T1[3], T1[4]), T1[5]);
      float m2 = fmaxf(fmaxf(T1[6], T1[7]), nd0);
      float vmax = fmaxf(fmaxf(m0, m1), fmaxf(m2, ndc1));
      unsigned ue = (__float_as_uint(vmax) >> 23) & 0xFFu;
      int e = (int)ue - 126;
      float sc = ldexpf(1.0f, -e);
      if (PH == 1) {
#pragma unroll
        for (int k = 0; k < G; ++k) EpF[k] = T1[k] * sc;
        dc0 = nd0 * sc; dc1 = ndc1 * sc; dc2 = EpF[G - 1];
        kaccF = knew + e;
      } else {
#pragma unroll
        for (int k = 0; k < G; ++k) EpF[k] = act ? T1[k] * sc : EpF[k];
        dc0 = act ? nd0 * sc : dc0;
        dc1 = act ? ndc1 * sc : dc1;
        dc2 = act ? EpF[G - 1] : dc2;
        kaccF = act ? knew + e : kaccF;
      }
      cxA = nxA; cdx = ndx; cex = nex;    // small rotation (3 float2)
    };
    std::integral_constant<int, 0> P0;
    std::integral_constant<int, 1> P1;
    std::integral_constant<int, 2> P2;
    for (int t = 0; t < 64; t += 2) {
      bstep(t, P0, sBk0, eBk0, sBk1, eBk1);
      bstep(t + 1, P0, sBk1, eBk1, sBk0, eBk0);
    }
    for (int t = 64; t < 128; t += 2) {
      bstep(t, P1, sBk0, eBk0, sBk1, eBk1);
      bstep(t + 1, P1, sBk1, eBk1, sBk0, eBk0);
    }
    for (int t = 128; t < 192; t += 2) {       // t=191 inert (all p >= NPH)
      bstep(t, P2, sBk0, eBk0, sBk1, eBk1);
      bstep(t + 1, P2, sBk1, eBk1, sBk0, eBk0);
    }
#pragma unroll
    for (int k = 0; k < G; ++k) {
      float le = (EpF[k] > 0.0f) ? __logf(EpF[k]) : NEG_BIG;
      LG[511 - (8 * j + k)] = le + (float)kaccF * LN2F - (float)(255 + 8 * j + k);
    }
  }
  __syncthreads();

  // ---- combine (R14 verbatim) ----
  {
    const float sx = xb[256];
    const float dxs = sx - xb[255];
    const float ex2s = __expf(-dxs * dxs);
#pragma unroll
    for (int c = 0; c < 4; ++c) {
      int jj = 4 * tid + c;
      float d = sx - yb[jj];
      float m2 = d * d;
      float lw = (dxs * d > 0.0f) ? __logf(ex2s + __expf(-m2)) : 0.0f;
      float t1 = ((jj > 0) ? LF[jj - 1] : NEG_BIG) - m2;
      float t2 = LF[jj] - 1.0f + lw;
      float mt = fmaxf(t1, t2);
      float term = NEG_BIG;
      if (mt > -1e29f)
        term = LG[jj] + mt + __logf(__expf(t1 - mt) + __expf(t2 - mt));
      TERMS[jj] = term;
    }
  }
  __syncthreads();
  if (wv == 0) {
    float v[8];
    float M = NEG_BIG;
#pragma unroll
    for (int i = 0; i < 8; ++i) {
      v[i] = TERMS[8 * j + i];
      M = fmaxf(M, v[i]);
    }
#pragma unroll
    for (int off = 1; off < 64; off <<= 1) M = fmaxf(M, __shfl_xor(M, off));
    float S = 0.0f;
#pragma unroll
    for (int i = 0; i < 8; ++i) S += __expf(v[i] - M);
#pragma unroll
    for (int off = 1; off < 64; off <<= 1) S += __shfl_xor(S, off);
    if (j == 0) ws[b] = -(M + __logf(S));
  }
}

__global__ __launch_bounds__(64) void reduce_kernel(const float* __restrict__ ws,
                                                    float* __restrict__ out) {
  float v = ws[threadIdx.x];
#pragma unroll
  for (int off = 32; off > 0; off >>= 1) v += __shfl_down(v, off);
  if (threadIdx.x == 0) out[0] = v * (1.0f / BATCH);
}

extern "C" void kernel_launch(void* const* d_in, const int* in_sizes, int n_in,
                              void* d_out, int out_size, void* d_ws, size_t ws_size,
                              hipStream_t stream) {
  const float* x = (const float*)d_in[0];
  const float* y = (const float*)d_in[1];
  float* ws = (float*)d_ws;
  float* out = (float*)d_out;
  msm_kernel<<<BATCH, 128, 0, stream>>>(x, y, ws);
  reduce_kernel<<<1, 64, 0, stream>>>(ws, out);
}